// Round 1
// 131.419 us; speedup vs baseline: 3.7916x; 3.7916x over previous
//
#include <hip/hip_runtime.h>

#define E_DIM 768

__device__ __forceinline__ unsigned short f2bf(float f) {
    union { float f; unsigned int u; } v; v.f = f;
    unsigned int u = v.u;
    return (unsigned short)((u + 0x7FFFu + ((u >> 16) & 1u)) >> 16);
}
__device__ __forceinline__ float bfu_lo(unsigned int u) {
    union { unsigned int u; float f; } v; v.u = u << 16; return v.f;
}
__device__ __forceinline__ float bfu_hi(unsigned int u) {
    union { unsigned int u; float f; } v; v.u = u & 0xFFFF0000u; return v.f;
}

// K1: A = he_a @ Wa^T + ba ; C = he_p @ Wc^T + bc (fp32 VALU), packed bf16 into dst:
// per b (128KB): A_b = 16384 uints ([i][hp], h pair packed), then C_b = 16384 uints.
__global__ __launch_bounds__(256) void k_proj_valu(
    const float* __restrict__ he_a, const float* __restrict__ Wa, const float* __restrict__ ba,
    const float* __restrict__ he_p, const float* __restrict__ Wc, const float* __restrict__ bc,
    unsigned int* __restrict__ dst)
{
    __shared__ float Xl[64 * 33];
    __shared__ float Wl[64 * 33];
    int bid = blockIdx.x;
    int which = bid >> 8;          // 0 = A, 1 = C
    int bidl = bid & 255;
    const float* X_g = which ? he_p : he_a;
    const float* W_g = which ? Wc : Wa;
    const float* bias = which ? bc : ba;
    int mbase = (bidl >> 3) * 64;   // global row (b*64+i), 32 row-tiles
    int hbase = (bidl & 7) * 64;    // 8 h-tiles
    int t = threadIdx.x;
    int ty = t >> 4, tx = t & 15;
    float acc[4][4] = {};
    for (int e0 = 0; e0 < E_DIM; e0 += 32) {
        __syncthreads();
#pragma unroll
        for (int it = 0; it < 2; ++it) {
            int idx = t + it * 256;
            int row = idx >> 3, c4 = idx & 7;
            float4 xv = *(const float4*)(X_g + (size_t)(mbase + row) * E_DIM + e0 + c4 * 4);
            Xl[row * 33 + c4 * 4 + 0] = xv.x; Xl[row * 33 + c4 * 4 + 1] = xv.y;
            Xl[row * 33 + c4 * 4 + 2] = xv.z; Xl[row * 33 + c4 * 4 + 3] = xv.w;
            float4 wv = *(const float4*)(W_g + (size_t)(hbase + row) * E_DIM + e0 + c4 * 4);
            Wl[row * 33 + c4 * 4 + 0] = wv.x; Wl[row * 33 + c4 * 4 + 1] = wv.y;
            Wl[row * 33 + c4 * 4 + 2] = wv.z; Wl[row * 33 + c4 * 4 + 3] = wv.w;
        }
        __syncthreads();
#pragma unroll 4
        for (int e = 0; e < 32; ++e) {
            float xr[4], wc[4];
#pragma unroll
            for (int r = 0; r < 4; ++r) xr[r] = Xl[(ty * 4 + r) * 33 + e];
#pragma unroll
            for (int c = 0; c < 4; ++c) wc[c] = Wl[(tx * 4 + c) * 33 + e];
#pragma unroll
            for (int r = 0; r < 4; ++r)
#pragma unroll
                for (int c = 0; c < 4; ++c) acc[r][c] = fmaf(xr[r], wc[c], acc[r][c]);
        }
    }
    int ocol = hbase + tx * 4;
#pragma unroll
    for (int r = 0; r < 4; ++r) {
        int grow = mbase + ty * 4 + r;        // = b*64 + i
        int b = grow >> 6, i = grow & 63;
        float v0 = acc[r][0] + bias[ocol + 0];
        float v1 = acc[r][1] + bias[ocol + 1];
        float v2 = acc[r][2] + bias[ocol + 2];
        float v3 = acc[r][3] + bias[ocol + 3];
        unsigned int u0 = (unsigned int)f2bf(v0) | ((unsigned int)f2bf(v1) << 16);
        unsigned int u1 = (unsigned int)f2bf(v2) | ((unsigned int)f2bf(v3) << 16);
        size_t base = (size_t)b * 32768 + (which ? 16384 : 0) + ((i * 512 + ocol) >> 1);
        dst[base] = u0;
        dst[base + 1] = u1;
    }
}

// K2: NK=1 -> one (b,k) per block, grid 256 (b = bid&31, k = bid>>5, same-b on same XCD).
//     NK=8 -> fallback, one b per block (grid 32), src may alias the att output region.
// Both A and C staged row-major [64][256 uints], LDS row stride 260 (16B aligned, <=2-way banks).
template<int NK>
__global__ __launch_bounds__(256) void k_att(
    float* __restrict__ out, const unsigned int* __restrict__ src,
    const float* __restrict__ Watt, const float* __restrict__ Wsc,
    float* __restrict__ partials)
{
    __shared__ unsigned int Al[64 * 260];
    __shared__ unsigned int Cl[64 * 260];
    __shared__ float Wattl[512], Wscl[512];
    __shared__ float red[4];
    int t = threadIdx.x;
    int lane = t & 63, wave = t >> 6;
    int b, k0;
    if (NK == 1) { b = blockIdx.x & 31; k0 = blockIdx.x >> 5; }
    else         { b = blockIdx.x;      k0 = 0; }
    const unsigned int* srcb = src + (size_t)b * 32768;

    if (NK == 1) {
        // 16B-aligned vector staging (src is the d_ws scratch, 16B aligned)
        const uint4* s4p = (const uint4*)srcb;
        for (int s4 = t; s4 < 4096; s4 += 256) {
            int row = s4 >> 6, hp = (s4 & 63) * 4;
            uint4 va = s4p[s4];
            uint4 vc = s4p[4096 + s4];
            *(uint4*)&Al[row * 260 + hp] = va;
            *(uint4*)&Cl[row * 260 + hp] = vc;
        }
    } else {
        for (int s = t; s < 16384; s += 256) {
            int row = s >> 8, hp = s & 255;
            Al[row * 260 + hp] = srcb[s];
            Cl[row * 260 + hp] = srcb[16384 + s];
        }
    }

    int i = t >> 2;            // row 0..63
    int jb = (t & 3) * 16;     // col block
    float* attreg = out + 33 + (size_t)b * 32768;
    float blocktotal = 0.f;

    for (int kk = 0; kk < NK; ++kk) {
        int k = k0 + kk;
        for (int s = t; s < 512; s += 256) {
            Wattl[s] = Watt[k * 512 + s];
            Wscl[s]  = Wsc[k * 512 + s];
        }
        __syncthreads();
        float sacc[16] = {}, gacc[16] = {};
        const unsigned int* Arow = &Al[i * 260];
        const unsigned int* Crow = &Cl[jb * 260];
        for (int hp = 0; hp < 256; hp += 2) {
            uint2 au = *(const uint2*)&Arow[hp];
            float a0 = bfu_lo(au.x), a1 = bfu_hi(au.x);
            float a2 = bfu_lo(au.y), a3 = bfu_hi(au.y);
            int h0 = hp * 2;
            float4 wk = *(const float4*)&Wattl[h0];
            float4 wg = *(const float4*)&Wscl[h0];
            float ak0 = a0 * wk.x, ak1 = a1 * wk.y, ak2 = a2 * wk.z, ak3 = a3 * wk.w;
            float ag0 = a0 * wg.x, ag1 = a1 * wg.y, ag2 = a2 * wg.z, ag3 = a3 * wg.w;
#pragma unroll
            for (int q = 0; q < 16; ++q) {
                uint2 cu = *(const uint2*)&Crow[q * 260 + hp];
                float c0 = bfu_lo(cu.x), c1 = bfu_hi(cu.x);
                float c2 = bfu_lo(cu.y), c3 = bfu_hi(cu.y);
                sacc[q] = fmaf(ak0, c0, sacc[q]);
                sacc[q] = fmaf(ak1, c1, sacc[q]);
                sacc[q] = fmaf(ak2, c2, sacc[q]);
                sacc[q] = fmaf(ak3, c3, sacc[q]);
                gacc[q] = fmaf(ag0, c0, gacc[q]);
                gacc[q] = fmaf(ag1, c1, gacc[q]);
                gacc[q] = fmaf(ag2, c2, gacc[q]);
                gacc[q] = fmaf(ag3, c3, gacc[q]);
            }
        }
        // block max
        float lmax = sacc[0];
#pragma unroll
        for (int e = 1; e < 16; ++e) lmax = fmaxf(lmax, sacc[e]);
        float v = lmax;
#pragma unroll
        for (int off = 32; off > 0; off >>= 1) v = fmaxf(v, __shfl_xor(v, off));
        if (lane == 0) red[wave] = v;
        __syncthreads();
        float M = fmaxf(fmaxf(red[0], red[1]), fmaxf(red[2], red[3]));
        __syncthreads();
        // exp + block sum
        float lsum = 0.f;
#pragma unroll
        for (int e = 0; e < 16; ++e) {
            sacc[e] = __expf(sacc[e] - M);
            lsum += sacc[e];
        }
        v = lsum;
#pragma unroll
        for (int off = 32; off > 0; off >>= 1) v += __shfl_xor(v, off);
        if (lane == 0) red[wave] = v;
        __syncthreads();
        float Z = red[0] + red[1] + red[2] + red[3];
        float inv = 1.0f / Z;
        __syncthreads();   // everyone done reading red before reuse
        // att write + partial score
        float pacc = 0.f;
        float* attk = attreg + k * 4096 + i * 64 + jb;
#pragma unroll
        for (int e = 0; e < 16; ++e) {
            float att = sacc[e] * inv;
            attk[e] = att;
            pacc += att * gacc[e];
        }
        v = pacc;
#pragma unroll
        for (int off = 32; off > 0; off >>= 1) v += __shfl_xor(v, off);
        if (lane == 0) red[wave] = v;
        __syncthreads();
        if (t == 0) {
            float tot = red[0] + red[1] + red[2] + red[3];
            if (NK == 1) partials[b * 8 + k] = tot;
            else blocktotal += tot;
        }
        __syncthreads();   // guard red/W reuse next k
    }
    if (NK == 8 && t == 0) out[b] = blocktotal;
}

// K3: score_p[b] = (sum_k partial) + bscore ; loss = mean((score - he_neg)^2) -> out[32]
__global__ __launch_bounds__(64) void k_loss(
    float* __restrict__ out, const float* __restrict__ he_neg,
    const float* __restrict__ partials, const float* __restrict__ bsc)
{
    __shared__ float sq[32];
    int t = threadIdx.x;
    if (t < 32) {
        float s;
        if (partials) {
            s = 0.f;
            for (int k = 0; k < 8; ++k) s += partials[t * 8 + k];
        } else {
            s = out[t];
        }
        s += bsc[0];
        out[t] = s;
        float d = s - he_neg[t];
        sq[t] = d * d;
    }
    __syncthreads();
    if (t == 0) {
        float l = 0.f;
        for (int i2 = 0; i2 < 32; ++i2) l += sq[i2];
        out[32] = l * (1.0f / 32.0f);
    }
}

extern "C" void kernel_launch(void* const* d_in, const int* in_sizes, int n_in,
                              void* d_out, int out_size, void* d_ws, size_t ws_size,
                              hipStream_t stream) {
    // Resolve input order at runtime from the size signature.
    // dict order:        he_a(1572864) he_p(1572864) he_n(32) Wa(393216) ba(512)
    //                    Wc(393216) bc(512) Watt(4096) batt(8) Wscore(4096) bscore(1)
    // alphabetical:      Wa Watt Wc Wscore ba batt bc bscore he_anchor he_neg he_pos
    int iA = 0, iP = 1, iN = 2, iWa = 3, iBa = 4, iWc = 5, iBc = 6, iWatt = 7, iWsc = 9, iBsc = 10;
    if (!(in_sizes[0] == 1572864 && in_sizes[2] == 32)) {
        if (n_in == 11 && in_sizes[0] == 393216 && in_sizes[8] == 1572864) {
            iWa = 0; iWatt = 1; iWc = 2; iWsc = 3; iBa = 4; iBc = 6; iBsc = 7;
            iA = 8; iN = 9; iP = 10;
        }
    }
    const float* he_a  = (const float*)d_in[iA];
    const float* he_p  = (const float*)d_in[iP];
    const float* he_n  = (const float*)d_in[iN];
    const float* Wa    = (const float*)d_in[iWa];
    const float* ba    = (const float*)d_in[iBa];
    const float* Wc    = (const float*)d_in[iWc];
    const float* bc    = (const float*)d_in[iBc];
    const float* Watt  = (const float*)d_in[iWatt];
    const float* Wsc   = (const float*)d_in[iWsc];
    const float* bsc   = (const float*)d_in[iBsc];
    float* out = (float*)d_out;

    size_t need = ((size_t)4 << 20) + 4096;   // A/C scratch (4MB) + partials
    if (d_ws != nullptr && ws_size >= need) {
        unsigned int* wsu = (unsigned int*)d_ws;
        float* partials = (float*)((char*)d_ws + ((size_t)4 << 20));
        k_proj_valu<<<dim3(512), dim3(256), 0, stream>>>(he_a, Wa, ba, he_p, Wc, bc, wsu);
        k_att<1><<<dim3(256), dim3(256), 0, stream>>>(out, wsu, Watt, Wsc, partials);
        k_loss<<<dim3(1), dim3(64), 0, stream>>>(out, he_n, partials, bsc);
    } else {
        // Fallback: pack A/C into the att region of d_out (race-free: one block per b).
        unsigned int* region = (unsigned int*)(out + 33);
        k_proj_valu<<<dim3(512), dim3(256), 0, stream>>>(he_a, Wa, ba, he_p, Wc, bc, region);
        k_att<8><<<dim3(32), dim3(256), 0, stream>>>(out, region, Watt, Wsc, nullptr);
        k_loss<<<dim3(1), dim3(64), 0, stream>>>(out, he_n, nullptr, bsc);
    }
}

// Round 2
// 81.626 us; speedup vs baseline: 6.1046x; 1.6100x over previous
//
#include <hip/hip_runtime.h>

#define E_DIM 768

typedef __attribute__((ext_vector_type(8))) short bf16x8;
typedef __attribute__((ext_vector_type(4))) float f32x4;

__device__ __forceinline__ unsigned short f2bf(float f) {
    union { float f; unsigned int u; } v; v.f = f;
    unsigned int u = v.u;
    return (unsigned short)((u + 0x7FFFu + ((u >> 16) & 1u)) >> 16);
}
__device__ __forceinline__ float bfu_lo(unsigned int u) {
    union { unsigned int u; float f; } v; v.u = u << 16; return v.f;
}
__device__ __forceinline__ float bfu_hi(unsigned int u) {
    union { unsigned int u; float f; } v; v.u = u & 0xFFFF0000u; return v.f;
}
__device__ __forceinline__ unsigned int cvt_pk_bf16(float lo, float hi) {
    unsigned int u;
    asm("v_cvt_pk_bf16_f32 %0, %1, %2" : "=v"(u) : "v"(lo), "v"(hi));
    return u;
}

// K1 (MFMA): A = he_a @ Wa^T + ba ; C = he_p @ Wc^T + bc, computed with bf16 MFMA
// (downstream consumes bf16 anyway). Output packed bf16, per b (128KB):
// A_b = 16384 uints ([i][hp]), then C_b = 16384 uints.
// Grid 256: which = bid>>7, mtile = (bid&127)>>3 (128 rows), htile = bid&7 (64 cols).
// 4 waves: wave-tile 64x32 = acc[4][2] of 16x16x32 frags; K-loop 24 x BK=32.
__global__ __launch_bounds__(256) void k_proj_mfma(
    const float* __restrict__ he_a, const float* __restrict__ Wa, const float* __restrict__ ba,
    const float* __restrict__ he_p, const float* __restrict__ Wc, const float* __restrict__ bc,
    unsigned short* __restrict__ dsts)
{
    __shared__ unsigned short Xs[128 * 40];   // [row][k], stride 40 bf16 (80B: <=2-way banks)
    __shared__ unsigned short Wl[64 * 40];
    int bid = blockIdx.x;
    int which = bid >> 7;
    int loc = bid & 127;
    int mbase = (loc >> 3) * 128;   // row in [0,2048) = b*64+i
    int hbase = (loc & 7) * 64;     // h col tile
    const float* Xg = which ? he_p : he_a;
    const float* Wg = which ? Wc : Wa;
    const float* bias = which ? bc : ba;
    int t = threadIdx.x;
    int lane = t & 63, w = t >> 6;
    int wr = w >> 1, wc = w & 1;    // wave -> 64x32 sub-tile

    float4 xr4[4];
    float4 wr4[2];
    // prefetch K-step 0
#pragma unroll
    for (int it = 0; it < 4; ++it) {
        int idx = t + it * 256; int row = idx >> 3, c4 = idx & 7;
        xr4[it] = *(const float4*)(Xg + (size_t)(mbase + row) * E_DIM + c4 * 4);
    }
#pragma unroll
    for (int it = 0; it < 2; ++it) {
        int idx = t + it * 256; int row = idx >> 3, c4 = idx & 7;
        wr4[it] = *(const float4*)(Wg + (size_t)(hbase + row) * E_DIM + c4 * 4);
    }

    f32x4 acc[4][2] = {};
    for (int kt = 0; kt < 24; ++kt) {
        __syncthreads();   // all waves done reading LDS from previous step
        // convert + stage current step
#pragma unroll
        for (int it = 0; it < 4; ++it) {
            int idx = t + it * 256; int row = idx >> 3, c4 = idx & 7;
            uint2 u = make_uint2(cvt_pk_bf16(xr4[it].x, xr4[it].y),
                                 cvt_pk_bf16(xr4[it].z, xr4[it].w));
            *(uint2*)&Xs[row * 40 + c4 * 4] = u;
        }
#pragma unroll
        for (int it = 0; it < 2; ++it) {
            int idx = t + it * 256; int row = idx >> 3, c4 = idx & 7;
            uint2 u = make_uint2(cvt_pk_bf16(wr4[it].x, wr4[it].y),
                                 cvt_pk_bf16(wr4[it].z, wr4[it].w));
            *(uint2*)&Wl[row * 40 + c4 * 4] = u;
        }
        // issue next step's global loads (in flight across the MFMA phase)
        if (kt < 23) {
            int e0 = (kt + 1) * 32;
#pragma unroll
            for (int it = 0; it < 4; ++it) {
                int idx = t + it * 256; int row = idx >> 3, c4 = idx & 7;
                xr4[it] = *(const float4*)(Xg + (size_t)(mbase + row) * E_DIM + e0 + c4 * 4);
            }
#pragma unroll
            for (int it = 0; it < 2; ++it) {
                int idx = t + it * 256; int row = idx >> 3, c4 = idx & 7;
                wr4[it] = *(const float4*)(Wg + (size_t)(hbase + row) * E_DIM + e0 + c4 * 4);
            }
        }
        __syncthreads();   // staged tile visible
        int ar = lane & 15;
        int k0 = (lane >> 4) * 8;
        bf16x8 af[4], bfr[2];
#pragma unroll
        for (int mi = 0; mi < 4; ++mi)
            af[mi] = *(const bf16x8*)&Xs[(wr * 64 + mi * 16 + ar) * 40 + k0];
#pragma unroll
        for (int ni = 0; ni < 2; ++ni)
            bfr[ni] = *(const bf16x8*)&Wl[(wc * 32 + ni * 16 + ar) * 40 + k0];
#pragma unroll
        for (int mi = 0; mi < 4; ++mi)
#pragma unroll
            for (int ni = 0; ni < 2; ++ni)
                acc[mi][ni] = __builtin_amdgcn_mfma_f32_16x16x32_bf16(
                    af[mi], bfr[ni], acc[mi][ni], 0, 0, 0);
    }
    // epilogue: bias + bf16 store. D map: col = lane&15, row = (lane>>4)*4 + reg.
#pragma unroll
    for (int ni = 0; ni < 2; ++ni) {
        int h = hbase + wc * 32 + ni * 16 + (lane & 15);
        float bv = bias[h];
#pragma unroll
        for (int mi = 0; mi < 4; ++mi) {
#pragma unroll
            for (int r = 0; r < 4; ++r) {
                int grow = mbase + wr * 64 + mi * 16 + (lane >> 4) * 4 + r;  // b*64+i
                int b = grow >> 6, i = grow & 63;
                float v = acc[mi][ni][r] + bv;
                dsts[(size_t)b * 65536 + (which ? 32768 : 0) + i * 512 + h] = f2bf(v);
            }
        }
    }
}

// K2: NK=1 -> one (b,k) per block, grid 256 (b = bid&31, k = bid>>5, same-b on same XCD).
//     NK=8 -> fallback, one b per block (grid 32), src may alias the att output region.
// Both A and C staged row-major [64][256 uints], LDS row stride 260 (16B aligned, <=2-way banks).
template<int NK>
__global__ __launch_bounds__(256) void k_att(
    float* __restrict__ out, const unsigned int* __restrict__ src,
    const float* __restrict__ Watt, const float* __restrict__ Wsc,
    float* __restrict__ partials)
{
    __shared__ unsigned int Al[64 * 260];
    __shared__ unsigned int Cl[64 * 260];
    __shared__ float Wattl[512], Wscl[512];
    __shared__ float red[4];
    int t = threadIdx.x;
    int lane = t & 63, wave = t >> 6;
    int b, k0;
    if (NK == 1) { b = blockIdx.x & 31; k0 = blockIdx.x >> 5; }
    else         { b = blockIdx.x;      k0 = 0; }
    const unsigned int* srcb = src + (size_t)b * 32768;

    if (NK == 1) {
        const uint4* s4p = (const uint4*)srcb;
        for (int s4 = t; s4 < 4096; s4 += 256) {
            int row = s4 >> 6, hp = (s4 & 63) * 4;
            uint4 va = s4p[s4];
            uint4 vc = s4p[4096 + s4];
            *(uint4*)&Al[row * 260 + hp] = va;
            *(uint4*)&Cl[row * 260 + hp] = vc;
        }
    } else {
        for (int s = t; s < 16384; s += 256) {
            int row = s >> 8, hp = s & 255;
            Al[row * 260 + hp] = srcb[s];
            Cl[row * 260 + hp] = srcb[16384 + s];
        }
    }

    int i = t >> 2;            // row 0..63
    int jb = (t & 3) * 16;     // col block
    float* attreg = out + 33 + (size_t)b * 32768;
    float blocktotal = 0.f;

    for (int kk = 0; kk < NK; ++kk) {
        int k = k0 + kk;
        for (int s = t; s < 512; s += 256) {
            Wattl[s] = Watt[k * 512 + s];
            Wscl[s]  = Wsc[k * 512 + s];
        }
        __syncthreads();
        float sacc[16] = {}, gacc[16] = {};
        const unsigned int* Arow = &Al[i * 260];
        const unsigned int* Crow = &Cl[jb * 260];
        for (int hp = 0; hp < 256; hp += 2) {
            uint2 au = *(const uint2*)&Arow[hp];
            float a0 = bfu_lo(au.x), a1 = bfu_hi(au.x);
            float a2 = bfu_lo(au.y), a3 = bfu_hi(au.y);
            int h0 = hp * 2;
            float4 wk = *(const float4*)&Wattl[h0];
            float4 wg = *(const float4*)&Wscl[h0];
            float ak0 = a0 * wk.x, ak1 = a1 * wk.y, ak2 = a2 * wk.z, ak3 = a3 * wk.w;
            float ag0 = a0 * wg.x, ag1 = a1 * wg.y, ag2 = a2 * wg.z, ag3 = a3 * wg.w;
#pragma unroll
            for (int q = 0; q < 16; ++q) {
                uint2 cu = *(const uint2*)&Crow[q * 260 + hp];
                float c0 = bfu_lo(cu.x), c1 = bfu_hi(cu.x);
                float c2 = bfu_lo(cu.y), c3 = bfu_hi(cu.y);
                sacc[q] = fmaf(ak0, c0, sacc[q]);
                sacc[q] = fmaf(ak1, c1, sacc[q]);
                sacc[q] = fmaf(ak2, c2, sacc[q]);
                sacc[q] = fmaf(ak3, c3, sacc[q]);
                gacc[q] = fmaf(ag0, c0, gacc[q]);
                gacc[q] = fmaf(ag1, c1, gacc[q]);
                gacc[q] = fmaf(ag2, c2, gacc[q]);
                gacc[q] = fmaf(ag3, c3, gacc[q]);
            }
        }
        // block max
        float lmax = sacc[0];
#pragma unroll
        for (int e = 1; e < 16; ++e) lmax = fmaxf(lmax, sacc[e]);
        float v = lmax;
#pragma unroll
        for (int off = 32; off > 0; off >>= 1) v = fmaxf(v, __shfl_xor(v, off));
        if (lane == 0) red[wave] = v;
        __syncthreads();
        float M = fmaxf(fmaxf(red[0], red[1]), fmaxf(red[2], red[3]));
        __syncthreads();
        // exp + block sum
        float lsum = 0.f;
#pragma unroll
        for (int e = 0; e < 16; ++e) {
            sacc[e] = __expf(sacc[e] - M);
            lsum += sacc[e];
        }
        v = lsum;
#pragma unroll
        for (int off = 32; off > 0; off >>= 1) v += __shfl_xor(v, off);
        if (lane == 0) red[wave] = v;
        __syncthreads();
        float Z = red[0] + red[1] + red[2] + red[3];
        float inv = 1.0f / Z;
        __syncthreads();   // everyone done reading red before reuse
        // att write + partial score
        float pacc = 0.f;
        float* attk = attreg + k * 4096 + i * 64 + jb;
#pragma unroll
        for (int e = 0; e < 16; ++e) {
            float att = sacc[e] * inv;
            attk[e] = att;
            pacc += att * gacc[e];
        }
        v = pacc;
#pragma unroll
        for (int off = 32; off > 0; off >>= 1) v += __shfl_xor(v, off);
        if (lane == 0) red[wave] = v;
        __syncthreads();
        if (t == 0) {
            float tot = red[0] + red[1] + red[2] + red[3];
            if (NK == 1) partials[b * 8 + k] = tot;
            else blocktotal += tot;
        }
        __syncthreads();   // guard red/W reuse next k
    }
    if (NK == 8 && t == 0) out[b] = blocktotal;
}

// K3: score_p[b] = (sum_k partial) + bscore ; loss = mean((score - he_neg)^2) -> out[32]
__global__ __launch_bounds__(64) void k_loss(
    float* __restrict__ out, const float* __restrict__ he_neg,
    const float* __restrict__ partials, const float* __restrict__ bsc)
{
    __shared__ float sq[32];
    int t = threadIdx.x;
    if (t < 32) {
        float s;
        if (partials) {
            s = 0.f;
            for (int k = 0; k < 8; ++k) s += partials[t * 8 + k];
        } else {
            s = out[t];
        }
        s += bsc[0];
        out[t] = s;
        float d = s - he_neg[t];
        sq[t] = d * d;
    }
    __syncthreads();
    if (t == 0) {
        float l = 0.f;
        for (int i2 = 0; i2 < 32; ++i2) l += sq[i2];
        out[32] = l * (1.0f / 32.0f);
    }
}

extern "C" void kernel_launch(void* const* d_in, const int* in_sizes, int n_in,
                              void* d_out, int out_size, void* d_ws, size_t ws_size,
                              hipStream_t stream) {
    // Resolve input order at runtime from the size signature.
    // dict order:        he_a(1572864) he_p(1572864) he_n(32) Wa(393216) ba(512)
    //                    Wc(393216) bc(512) Watt(4096) batt(8) Wscore(4096) bscore(1)
    // alphabetical:      Wa Watt Wc Wscore ba batt bc bscore he_anchor he_neg he_pos
    int iA = 0, iP = 1, iN = 2, iWa = 3, iBa = 4, iWc = 5, iBc = 6, iWatt = 7, iWsc = 9, iBsc = 10;
    if (!(in_sizes[0] == 1572864 && in_sizes[2] == 32)) {
        if (n_in == 11 && in_sizes[0] == 393216 && in_sizes[8] == 1572864) {
            iWa = 0; iWatt = 1; iWc = 2; iWsc = 3; iBa = 4; iBc = 6; iBsc = 7;
            iA = 8; iN = 9; iP = 10;
        }
    }
    const float* he_a  = (const float*)d_in[iA];
    const float* he_p  = (const float*)d_in[iP];
    const float* he_n  = (const float*)d_in[iN];
    const float* Wa    = (const float*)d_in[iWa];
    const float* ba    = (const float*)d_in[iBa];
    const float* Wc    = (const float*)d_in[iWc];
    const float* bc    = (const float*)d_in[iBc];
    const float* Watt  = (const float*)d_in[iWatt];
    const float* Wsc   = (const float*)d_in[iWsc];
    const float* bsc   = (const float*)d_in[iBsc];
    float* out = (float*)d_out;

    size_t need = ((size_t)4 << 20) + 4096;   // A/C scratch (4MB) + partials
    if (d_ws != nullptr && ws_size >= need) {
        unsigned short* wss = (unsigned short*)d_ws;
        float* partials = (float*)((char*)d_ws + ((size_t)4 << 20));
        k_proj_mfma<<<dim3(256), dim3(256), 0, stream>>>(he_a, Wa, ba, he_p, Wc, bc, wss);
        k_att<1><<<dim3(256), dim3(256), 0, stream>>>(out, (unsigned int*)wss, Watt, Wsc, partials);
        k_loss<<<dim3(1), dim3(64), 0, stream>>>(out, he_n, partials, bsc);
    } else {
        // Fallback: pack A/C into the att region of d_out (race-free: one block per b).
        unsigned short* region = (unsigned short*)(out + 33);
        k_proj_mfma<<<dim3(256), dim3(256), 0, stream>>>(he_a, Wa, ba, he_p, Wc, bc, region);
        k_att<8><<<dim3(32), dim3(256), 0, stream>>>(out, (unsigned int*)region, Watt, Wsc, nullptr);
        k_loss<<<dim3(1), dim3(64), 0, stream>>>(out, he_n, nullptr, bsc);
    }
}

// Round 3
// 49.956 us; speedup vs baseline: 9.9747x; 1.6340x over previous
//
#include <hip/hip_runtime.h>

#define E_DIM 768

typedef __attribute__((ext_vector_type(8))) short bf16x8;
typedef __attribute__((ext_vector_type(4))) float f32x4;

__device__ __forceinline__ unsigned short f2bf(float f) {
    union { float f; unsigned int u; } v; v.f = f;
    unsigned int u = v.u;
    return (unsigned short)((u + 0x7FFFu + ((u >> 16) & 1u)) >> 16);
}
__device__ __forceinline__ float bfu_lo(unsigned int u) {
    union { unsigned int u; float f; } v; v.u = u << 16; return v.f;
}
__device__ __forceinline__ float bfu_hi(unsigned int u) {
    union { unsigned int u; float f; } v; v.u = u & 0xFFFF0000u; return v.f;
}
__device__ __forceinline__ unsigned int cvt_pk_bf16(float lo, float hi) {
    unsigned int u;
    asm("v_cvt_pk_bf16_f32 %0, %1, %2" : "=v"(u) : "v"(lo), "v"(hi));
    return u;
}

// K1 (MFMA): A = he_a @ Wa^T + ba ; C = he_p @ Wc^T + bc, computed with bf16 MFMA.
// Output packed bf16, per b (128KB): A_b = 16384 uints ([i][hp]), then C_b = 16384 uints.
__global__ __launch_bounds__(256) void k_proj_mfma(
    const float* __restrict__ he_a, const float* __restrict__ Wa, const float* __restrict__ ba,
    const float* __restrict__ he_p, const float* __restrict__ Wc, const float* __restrict__ bc,
    unsigned short* __restrict__ dsts)
{
    __shared__ unsigned short Xs[128 * 40];   // [row][k], stride 40 bf16 (80B: <=2-way banks)
    __shared__ unsigned short Wl[64 * 40];
    int bid = blockIdx.x;
    int which = bid >> 7;
    int loc = bid & 127;
    int mbase = (loc >> 3) * 128;   // row in [0,2048) = b*64+i
    int hbase = (loc & 7) * 64;     // h col tile
    const float* Xg = which ? he_p : he_a;
    const float* Wg = which ? Wc : Wa;
    const float* bias = which ? bc : ba;
    int t = threadIdx.x;
    int lane = t & 63, w = t >> 6;
    int wr = w >> 1, wc = w & 1;    // wave -> 64x32 sub-tile

    float4 xr4[4];
    float4 wr4[2];
#pragma unroll
    for (int it = 0; it < 4; ++it) {
        int idx = t + it * 256; int row = idx >> 3, c4 = idx & 7;
        xr4[it] = *(const float4*)(Xg + (size_t)(mbase + row) * E_DIM + c4 * 4);
    }
#pragma unroll
    for (int it = 0; it < 2; ++it) {
        int idx = t + it * 256; int row = idx >> 3, c4 = idx & 7;
        wr4[it] = *(const float4*)(Wg + (size_t)(hbase + row) * E_DIM + c4 * 4);
    }

    f32x4 acc[4][2] = {};
    for (int kt = 0; kt < 24; ++kt) {
        __syncthreads();
#pragma unroll
        for (int it = 0; it < 4; ++it) {
            int idx = t + it * 256; int row = idx >> 3, c4 = idx & 7;
            uint2 u = make_uint2(cvt_pk_bf16(xr4[it].x, xr4[it].y),
                                 cvt_pk_bf16(xr4[it].z, xr4[it].w));
            *(uint2*)&Xs[row * 40 + c4 * 4] = u;
        }
#pragma unroll
        for (int it = 0; it < 2; ++it) {
            int idx = t + it * 256; int row = idx >> 3, c4 = idx & 7;
            uint2 u = make_uint2(cvt_pk_bf16(wr4[it].x, wr4[it].y),
                                 cvt_pk_bf16(wr4[it].z, wr4[it].w));
            *(uint2*)&Wl[row * 40 + c4 * 4] = u;
        }
        if (kt < 23) {
            int e0 = (kt + 1) * 32;
#pragma unroll
            for (int it = 0; it < 4; ++it) {
                int idx = t + it * 256; int row = idx >> 3, c4 = idx & 7;
                xr4[it] = *(const float4*)(Xg + (size_t)(mbase + row) * E_DIM + e0 + c4 * 4);
            }
#pragma unroll
            for (int it = 0; it < 2; ++it) {
                int idx = t + it * 256; int row = idx >> 3, c4 = idx & 7;
                wr4[it] = *(const float4*)(Wg + (size_t)(hbase + row) * E_DIM + e0 + c4 * 4);
            }
        }
        __syncthreads();
        int ar = lane & 15;
        int k0 = (lane >> 4) * 8;
        bf16x8 af[4], bfr[2];
#pragma unroll
        for (int mi = 0; mi < 4; ++mi)
            af[mi] = *(const bf16x8*)&Xs[(wr * 64 + mi * 16 + ar) * 40 + k0];
#pragma unroll
        for (int ni = 0; ni < 2; ++ni)
            bfr[ni] = *(const bf16x8*)&Wl[(wc * 32 + ni * 16 + ar) * 40 + k0];
#pragma unroll
        for (int mi = 0; mi < 4; ++mi)
#pragma unroll
            for (int ni = 0; ni < 2; ++ni)
                acc[mi][ni] = __builtin_amdgcn_mfma_f32_16x16x32_bf16(
                    af[mi], bfr[ni], acc[mi][ni], 0, 0, 0);
    }
#pragma unroll
    for (int ni = 0; ni < 2; ++ni) {
        int h = hbase + wc * 32 + ni * 16 + (lane & 15);
        float bv = bias[h];
#pragma unroll
        for (int mi = 0; mi < 4; ++mi) {
#pragma unroll
            for (int r = 0; r < 4; ++r) {
                int grow = mbase + wr * 64 + mi * 16 + (lane >> 4) * 4 + r;  // b*64+i
                int b = grow >> 6, i = grow & 63;
                float v = acc[mi][ni][r] + bv;
                dsts[(size_t)b * 65536 + (which ? 32768 : 0) + i * 512 + h] = f2bf(v);
            }
        }
    }
}

// K2 (MFMA): one (b,k) per block, grid 256 (b = bid&31, k = bid>>5 -> same-b on same XCD).
// S = (A .* Watt_k) @ C^T, G = (A .* Wsc_k) @ C^T via 16x16x32 bf16 MFMA, h-chunked (CH=128).
// LDS stride 136 bf16 (= 68 dwords): frag b128 reads are bank-uniform.
__global__ __launch_bounds__(256) void k_att_mfma(
    float* __restrict__ out, const unsigned int* __restrict__ src,
    const float* __restrict__ Watt, const float* __restrict__ Wsc,
    float* __restrict__ partials)
{
    __shared__ unsigned short AkL[64 * 136];
    __shared__ unsigned short AgL[64 * 136];
    __shared__ unsigned short CL[64 * 136];
    __shared__ float WlK[512], WlG[512];
    __shared__ float red[4];
    int t = threadIdx.x;
    int lane = t & 63, w = t >> 6;
    int b = blockIdx.x & 31, k = blockIdx.x >> 5;
    const unsigned int* Au = src + (size_t)b * 32768;
    const unsigned int* Cu = Au + 16384;

    for (int s = t; s < 512; s += 256) {
        WlK[s] = Watt[k * 512 + s];
        WlG[s] = Wsc[k * 512 + s];
    }

    int row = t >> 2, seg = t & 3;            // staging: row 0..63, 16-uint segment
    const unsigned int* Arp = Au + row * 256 + seg * 16;
    const unsigned int* Crp = Cu + row * 256 + seg * 16;
    uint4 rA[4], rC[4];
#pragma unroll
    for (int g = 0; g < 4; ++g) {
        rA[g] = *(const uint4*)(Arp + g * 4);
        rC[g] = *(const uint4*)(Crp + g * 4);
    }
    __syncthreads();   // W tables visible

    unsigned int* AkU = (unsigned int*)AkL;
    unsigned int* AgU = (unsigned int*)AgL;
    unsigned int* CU_ = (unsigned int*)CL;

    int arow = w * 16 + (lane & 15);
    int k0s = (lane >> 4) * 8;                // k offset (shorts) within 32-k step
    f32x4 accS[4] = {}, accG[4] = {};

    for (int c = 0; c < 4; ++c) {
        int hb = c * 128 + seg * 32;
#pragma unroll
        for (int g = 0; g < 4; ++g) {
            uint4 sv = rA[g];
            uint4 okv, ogv;
#pragma unroll
            for (int e = 0; e < 4; ++e) {
                unsigned int u = (&sv.x)[e];
                float a0 = bfu_lo(u), a1 = bfu_hi(u);
                int h0 = hb + (g * 4 + e) * 2;
                float2 wk = *(const float2*)&WlK[h0];
                float2 wg = *(const float2*)&WlG[h0];
                (&okv.x)[e] = cvt_pk_bf16(a0 * wk.x, a1 * wk.y);
                (&ogv.x)[e] = cvt_pk_bf16(a0 * wg.x, a1 * wg.y);
            }
            *(uint4*)&AkU[row * 68 + seg * 16 + g * 4] = okv;
            *(uint4*)&AgU[row * 68 + seg * 16 + g * 4] = ogv;
            *(uint4*)&CU_[row * 68 + seg * 16 + g * 4] = rC[g];
        }
        if (c < 3) {
#pragma unroll
            for (int g = 0; g < 4; ++g) {
                rA[g] = *(const uint4*)(Arp + (c + 1) * 64 + g * 4);
                rC[g] = *(const uint4*)(Crp + (c + 1) * 64 + g * 4);
            }
        }
        __syncthreads();
#pragma unroll
        for (int ks = 0; ks < 4; ++ks) {
            bf16x8 ak = *(const bf16x8*)&AkL[arow * 136 + ks * 32 + k0s];
            bf16x8 ag = *(const bf16x8*)&AgL[arow * 136 + ks * 32 + k0s];
#pragma unroll
            for (int ni = 0; ni < 4; ++ni) {
                bf16x8 cb = *(const bf16x8*)&CL[(ni * 16 + (lane & 15)) * 136 + ks * 32 + k0s];
                accS[ni] = __builtin_amdgcn_mfma_f32_16x16x32_bf16(ak, cb, accS[ni], 0, 0, 0);
                accG[ni] = __builtin_amdgcn_mfma_f32_16x16x32_bf16(ag, cb, accG[ni], 0, 0, 0);
            }
        }
        __syncthreads();
    }

    // block softmax over all 4096 logits (batt cancels in softmax)
    float lmax = accS[0][0];
#pragma unroll
    for (int ni = 0; ni < 4; ++ni)
#pragma unroll
        for (int r = 0; r < 4; ++r) lmax = fmaxf(lmax, accS[ni][r]);
    float v = lmax;
#pragma unroll
    for (int off = 32; off > 0; off >>= 1) v = fmaxf(v, __shfl_xor(v, off));
    if (lane == 0) red[w] = v;
    __syncthreads();
    float M = fmaxf(fmaxf(red[0], red[1]), fmaxf(red[2], red[3]));
    __syncthreads();
    float ev[16];
    float lsum = 0.f;
#pragma unroll
    for (int ni = 0; ni < 4; ++ni)
#pragma unroll
        for (int r = 0; r < 4; ++r) {
            float e = __expf(accS[ni][r] - M);
            ev[ni * 4 + r] = e;
            lsum += e;
        }
    v = lsum;
#pragma unroll
    for (int off = 32; off > 0; off >>= 1) v += __shfl_xor(v, off);
    if (lane == 0) red[w] = v;
    __syncthreads();
    float inv = 1.0f / (red[0] + red[1] + red[2] + red[3]);
    __syncthreads();
    float pacc = 0.f;
    float* attk = out + 33 + (size_t)b * 32768 + (size_t)k * 4096;
#pragma unroll
    for (int ni = 0; ni < 4; ++ni) {
        int j = ni * 16 + (lane & 15);
#pragma unroll
        for (int r = 0; r < 4; ++r) {
            int i = w * 16 + (lane >> 4) * 4 + r;
            float av = ev[ni * 4 + r] * inv;
            attk[i * 64 + j] = av;
            pacc += av * accG[ni][r];
        }
    }
    v = pacc;
#pragma unroll
    for (int off = 32; off > 0; off >>= 1) v += __shfl_xor(v, off);
    if (lane == 0) red[w] = v;
    __syncthreads();
    if (t == 0) partials[b * 8 + k] = red[0] + red[1] + red[2] + red[3];
}

// K2 fallback (no workspace): VALU version, one b per block, src aliases att region.
__global__ __launch_bounds__(256) void k_att_valu8(
    float* __restrict__ out, const unsigned int* __restrict__ src,
    const float* __restrict__ Watt, const float* __restrict__ Wsc)
{
    __shared__ unsigned int Al[64 * 260];
    __shared__ unsigned int Cl[64 * 260];
    __shared__ float Wattl[512], Wscl[512];
    __shared__ float red[4];
    int t = threadIdx.x;
    int lane = t & 63, wave = t >> 6;
    int b = blockIdx.x;
    const unsigned int* srcb = src + (size_t)b * 32768;

    for (int s = t; s < 16384; s += 256) {
        int row = s >> 8, hp = s & 255;
        Al[row * 260 + hp] = srcb[s];
        Cl[row * 260 + hp] = srcb[16384 + s];
    }

    int i = t >> 2;
    int jb = (t & 3) * 16;
    float* attreg = out + 33 + (size_t)b * 32768;
    float blocktotal = 0.f;

    for (int k = 0; k < 8; ++k) {
        for (int s = t; s < 512; s += 256) {
            Wattl[s] = Watt[k * 512 + s];
            Wscl[s]  = Wsc[k * 512 + s];
        }
        __syncthreads();
        float sacc[16] = {}, gacc[16] = {};
        const unsigned int* Arow = &Al[i * 260];
        const unsigned int* Crow = &Cl[jb * 260];
        for (int hp = 0; hp < 256; hp += 2) {
            uint2 au = *(const uint2*)&Arow[hp];
            float a0 = bfu_lo(au.x), a1 = bfu_hi(au.x);
            float a2 = bfu_lo(au.y), a3 = bfu_hi(au.y);
            int h0 = hp * 2;
            float4 wk = *(const float4*)&Wattl[h0];
            float4 wg = *(const float4*)&Wscl[h0];
            float ak0 = a0 * wk.x, ak1 = a1 * wk.y, ak2 = a2 * wk.z, ak3 = a3 * wk.w;
            float ag0 = a0 * wg.x, ag1 = a1 * wg.y, ag2 = a2 * wg.z, ag3 = a3 * wg.w;
#pragma unroll
            for (int q = 0; q < 16; ++q) {
                uint2 cu = *(const uint2*)&Crow[q * 260 + hp];
                float c0 = bfu_lo(cu.x), c1 = bfu_hi(cu.x);
                float c2 = bfu_lo(cu.y), c3 = bfu_hi(cu.y);
                sacc[q] = fmaf(ak0, c0, sacc[q]); gacc[q] = fmaf(ag0, c0, gacc[q]);
                sacc[q] = fmaf(ak1, c1, sacc[q]); gacc[q] = fmaf(ag1, c1, gacc[q]);
                sacc[q] = fmaf(ak2, c2, sacc[q]); gacc[q] = fmaf(ag2, c2, gacc[q]);
                sacc[q] = fmaf(ak3, c3, sacc[q]); gacc[q] = fmaf(ag3, c3, gacc[q]);
            }
        }
        float lmax = sacc[0];
#pragma unroll
        for (int e = 1; e < 16; ++e) lmax = fmaxf(lmax, sacc[e]);
        float v = lmax;
#pragma unroll
        for (int off = 32; off > 0; off >>= 1) v = fmaxf(v, __shfl_xor(v, off));
        if (lane == 0) red[wave] = v;
        __syncthreads();
        float M = fmaxf(fmaxf(red[0], red[1]), fmaxf(red[2], red[3]));
        __syncthreads();
        float lsum = 0.f;
#pragma unroll
        for (int e = 0; e < 16; ++e) {
            sacc[e] = __expf(sacc[e] - M);
            lsum += sacc[e];
        }
        v = lsum;
#pragma unroll
        for (int off = 32; off > 0; off >>= 1) v += __shfl_xor(v, off);
        if (lane == 0) red[wave] = v;
        __syncthreads();
        float Z = red[0] + red[1] + red[2] + red[3];
        float inv = 1.0f / Z;
        __syncthreads();
        float pacc = 0.f;
        float* attk = attreg + k * 4096 + i * 64 + jb;
#pragma unroll
        for (int e = 0; e < 16; ++e) {
            float att = sacc[e] * inv;
            attk[e] = att;
            pacc += att * gacc[e];
        }
        v = pacc;
#pragma unroll
        for (int off = 32; off > 0; off >>= 1) v += __shfl_xor(v, off);
        if (lane == 0) red[wave] = v;
        __syncthreads();
        if (t == 0) blocktotal += red[0] + red[1] + red[2] + red[3];
        __syncthreads();
    }
    if (t == 0) out[b] = blocktotal;
}

// K3: score_p[b] = (sum_k partial) + bscore ; loss = mean((score - he_neg)^2) -> out[32]
__global__ __launch_bounds__(64) void k_loss(
    float* __restrict__ out, const float* __restrict__ he_neg,
    const float* __restrict__ partials, const float* __restrict__ bsc)
{
    __shared__ float sq[32];
    int t = threadIdx.x;
    if (t < 32) {
        float s;
        if (partials) {
            s = 0.f;
            for (int k = 0; k < 8; ++k) s += partials[t * 8 + k];
        } else {
            s = out[t];
        }
        s += bsc[0];
        out[t] = s;
        float d = s - he_neg[t];
        sq[t] = d * d;
    }
    __syncthreads();
    if (t == 0) {
        float l = 0.f;
        for (int i2 = 0; i2 < 32; ++i2) l += sq[i2];
        out[32] = l * (1.0f / 32.0f);
    }
}

extern "C" void kernel_launch(void* const* d_in, const int* in_sizes, int n_in,
                              void* d_out, int out_size, void* d_ws, size_t ws_size,
                              hipStream_t stream) {
    int iA = 0, iP = 1, iN = 2, iWa = 3, iBa = 4, iWc = 5, iBc = 6, iWatt = 7, iWsc = 9, iBsc = 10;
    if (!(in_sizes[0] == 1572864 && in_sizes[2] == 32)) {
        if (n_in == 11 && in_sizes[0] == 393216 && in_sizes[8] == 1572864) {
            iWa = 0; iWatt = 1; iWc = 2; iWsc = 3; iBa = 4; iBc = 6; iBsc = 7;
            iA = 8; iN = 9; iP = 10;
        }
    }
    const float* he_a  = (const float*)d_in[iA];
    const float* he_p  = (const float*)d_in[iP];
    const float* he_n  = (const float*)d_in[iN];
    const float* Wa    = (const float*)d_in[iWa];
    const float* ba    = (const float*)d_in[iBa];
    const float* Wc    = (const float*)d_in[iWc];
    const float* bc    = (const float*)d_in[iBc];
    const float* Watt  = (const float*)d_in[iWatt];
    const float* Wsc   = (const float*)d_in[iWsc];
    const float* bsc   = (const float*)d_in[iBsc];
    float* out = (float*)d_out;

    size_t need = ((size_t)4 << 20) + 4096;   // A/C scratch (4MB) + partials
    if (d_ws != nullptr && ws_size >= need) {
        unsigned short* wss = (unsigned short*)d_ws;
        float* partials = (float*)((char*)d_ws + ((size_t)4 << 20));
        k_proj_mfma<<<dim3(256), dim3(256), 0, stream>>>(he_a, Wa, ba, he_p, Wc, bc, wss);
        k_att_mfma<<<dim3(256), dim3(256), 0, stream>>>(out, (unsigned int*)wss, Watt, Wsc, partials);
        k_loss<<<dim3(1), dim3(64), 0, stream>>>(out, he_n, partials, bsc);
    } else {
        unsigned short* region = (unsigned short*)(out + 33);
        k_proj_mfma<<<dim3(256), dim3(256), 0, stream>>>(he_a, Wa, ba, he_p, Wc, bc, region);
        k_att_valu8<<<dim3(32), dim3(256), 0, stream>>>(out, (unsigned int*)region, Watt, Wsc);
        k_loss<<<dim3(1), dim3(64), 0, stream>>>(out, he_n, nullptr, bsc);
    }
}